// Round 2
// baseline (208.608 us; speedup 1.0000x reference)
//
#include <hip/hip_runtime.h>
#include <hip/hip_bf16.h>

#define BB 2
#define PP 128
#define CC 8
#define EE 1024
#define HH 16
#define KVHH 4
#define DD 64
#define TT 1024
#define EKVV 256

typedef unsigned short u16;
typedef unsigned int u32;
typedef __attribute__((ext_vector_type(8))) short bf16x8;
typedef __attribute__((ext_vector_type(4))) float f32x4;

__device__ __forceinline__ float b2f(u16 u) {
    u32 x = ((u32)u) << 16;
    return __uint_as_float(x);
}
__device__ __forceinline__ u16 f2b(float f) {
    u32 x = __float_as_uint(f);
    u32 r = (x + 0x7FFFu + ((x >> 16) & 1u)) >> 16;
    return (u16)r;
}

// async global->LDS 16B (wave-uniform LDS base + lane*16 layout required)
#define GLL16(gp, lp)                                                          \
    __builtin_amdgcn_global_load_lds(                                          \
        (__attribute__((address_space(1))) void*)(gp),                         \
        (__attribute__((address_space(3))) void*)(lp), 16, 0, 0)

// ---------------------------------------------------------------------------
// k_prep: one-time conversions + tkb/ckb zeroing.
//   blocks [0,1024):    hidden f32 -> bf16 (hb); blocks [0,34) also zero tkb/ckb
//   blocks [1024,2048): Wq   1024x1024 -> btq rows [0,1024)    (transposed bf16)
//   blocks [2048,2560): Wkv  1024x512  -> btq rows [1024,1536) (transposed bf16)
//   blocks [2560,3584): Wproj 1024x1024 -> btp                 (transposed bf16)
// ---------------------------------------------------------------------------
__global__ __launch_bounds__(256) void k_prep(const float* __restrict__ hidden,
                                              const float* __restrict__ Wq,
                                              const float* __restrict__ Wkv,
                                              const float* __restrict__ Wproj,
                                              u16* __restrict__ hb,
                                              u16* __restrict__ btq,
                                              u16* __restrict__ btp,
                                              float* __restrict__ tkb) {
    __shared__ float ts[32][33];
    int bid = blockIdx.x;
    int tid = threadIdx.x;
    if (bid < 1024) {
        if (bid < 34)  // zero tkb(32768)+ckb(2048) = 8704 float4
            ((float4*)tkb)[bid * 256 + tid] = make_float4(0.f, 0.f, 0.f, 0.f);
        int base = (bid * 256 + tid) * 8;
        float4 a0 = *(const float4*)(hidden + base);
        float4 a1 = *(const float4*)(hidden + base + 4);
        u16 o[8] = {f2b(a0.x), f2b(a0.y), f2b(a0.z), f2b(a0.w),
                    f2b(a1.x), f2b(a1.y), f2b(a1.z), f2b(a1.w)};
        *(uint4*)(hb + base) = *(uint4*)o;
        return;
    }
    bid -= 1024;
    const float* W;
    u16* out;
    int N, tk, tn;
    if (bid < 1024) {
        W = Wq; out = btq; N = 1024; tk = bid >> 5; tn = bid & 31;
    } else if (bid < 1536) {
        int b2 = bid - 1024;
        W = Wkv; out = btq + 1024 * 1024; N = 512; tk = b2 >> 4; tn = b2 & 15;
    } else {
        int b2 = bid - 1536;
        W = Wproj; out = btp; N = 1024; tk = b2 >> 5; tn = b2 & 31;
    }
    int r = tid >> 3, c4 = (tid & 7) << 2;
    float4 v = *(const float4*)(W + (size_t)(tk * 32 + r) * N + tn * 32 + c4);
    ts[r][c4 + 0] = v.x;
    ts[r][c4 + 1] = v.y;
    ts[r][c4 + 2] = v.z;
    ts[r][c4 + 3] = v.w;
    __syncthreads();
    u16 o[4] = {f2b(ts[c4 + 0][r]), f2b(ts[c4 + 1][r]),
                f2b(ts[c4 + 2][r]), f2b(ts[c4 + 3][r])};
    *(ushort4*)(out + (size_t)(tn * 32 + r) * 1024 + tk * 32 + c4) = *(ushort4*)o;
}

// ---------------------------------------------------------------------------
// sgemm_sk: split-K GEMM for the two tiny projections (unchanged).
// ---------------------------------------------------------------------------
__global__ __launch_bounds__(256) void sgemm_sk(const float* __restrict__ pos,
                                                const float* __restrict__ Wpos,
                                                const float* __restrict__ chan,
                                                const float* __restrict__ Wchan,
                                                float* __restrict__ tkb,
                                                float* __restrict__ ckb) {
    __shared__ float As[16][68];
    __shared__ float Bs[16][68];
    int tile = blockIdx.x;
    const float* A; const float* B; float* C; int M, m0, n0;
    if (tile < 8) { A = pos;  B = Wpos;  C = tkb; M = 128; m0 = (tile >> 2) * 64; n0 = (tile & 3) * 64; }
    else          { A = chan; B = Wchan; C = ckb; M = 8;   m0 = 0;               n0 = (tile - 8) * 64; }
    int kbase = blockIdx.y * 128;

    int tid = threadIdx.x;
    int tx = tid & 15, ty = tid >> 4;
    float acc[4][4];
#pragma unroll
    for (int r = 0; r < 4; r++)
#pragma unroll
        for (int c = 0; c < 4; c++) acc[r][c] = 0.f;

    int am = tid >> 2, ak = (tid & 3) << 2;
    int bk = tid >> 4, bn = (tid & 15) << 2;

    for (int k0 = kbase; k0 < kbase + 128; k0 += 16) {
        int row = m0 + am;
        float4 av;
        if (row < M) av = *reinterpret_cast<const float4*>(A + (size_t)row * 1024 + k0 + ak);
        else av = make_float4(0.f, 0.f, 0.f, 0.f);
        As[ak + 0][am] = av.x;
        As[ak + 1][am] = av.y;
        As[ak + 2][am] = av.z;
        As[ak + 3][am] = av.w;
        float4 bv = *reinterpret_cast<const float4*>(B + (size_t)(k0 + bk) * 256 + n0 + bn);
        Bs[bk][bn + 0] = bv.x;
        Bs[bk][bn + 1] = bv.y;
        Bs[bk][bn + 2] = bv.z;
        Bs[bk][bn + 3] = bv.w;
        __syncthreads();
#pragma unroll
        for (int kk = 0; kk < 16; kk++) {
            float4 a4 = *reinterpret_cast<const float4*>(&As[kk][ty << 2]);
            float4 b4 = *reinterpret_cast<const float4*>(&Bs[kk][tx << 2]);
            acc[0][0] += a4.x * b4.x; acc[0][1] += a4.x * b4.y; acc[0][2] += a4.x * b4.z; acc[0][3] += a4.x * b4.w;
            acc[1][0] += a4.y * b4.x; acc[1][1] += a4.y * b4.y; acc[1][2] += a4.y * b4.z; acc[1][3] += a4.y * b4.w;
            acc[2][0] += a4.z * b4.x; acc[2][1] += a4.z * b4.y; acc[2][2] += a4.z * b4.z; acc[2][3] += a4.z * b4.w;
            acc[3][0] += a4.w * b4.x; acc[3][1] += a4.w * b4.y; acc[3][2] += a4.w * b4.z; acc[3][3] += a4.w * b4.w;
        }
        __syncthreads();
    }
#pragma unroll
    for (int r = 0; r < 4; r++) {
        int row = m0 + (ty << 2) + r;
        if (row < M) {
#pragma unroll
            for (int c = 0; c < 4; c++) {
                int col = n0 + (tx << 2) + c;
                atomicAdd(&C[(size_t)row * 256 + col], acc[r][c]);
            }
        }
    }
}

// ---------------------------------------------------------------------------
// mgemm_qkv2: m97-structure bf16 GEMM (global_load_lds + 2-phase dbuf).
// A = hb [2048][1024] bf16, B = btq [1536][1024] bf16 (row = output col).
// V-half output (ntile 10,11) is written TRANSPOSED straight to vt
// (replaces the separate k_vt kernel).
// ---------------------------------------------------------------------------
__global__ __launch_bounds__(256) void mgemm_qkv2(const u16* __restrict__ Ab,
                                                  const u16* __restrict__ BT,
                                                  u16* __restrict__ qout,
                                                  u16* __restrict__ kvout,
                                                  u16* __restrict__ vtb) {
    __shared__ __align__(16) u16 As[2][128 * 32];
    __shared__ __align__(16) u16 Bs[2][128 * 32];
    int tid = threadIdx.x;
    int ntile = blockIdx.x;
    int m0 = blockIdx.y * 128;
    int n0g = ntile * 128;
    u16* Cout; int BN, n0;
    if (ntile < 8) { Cout = qout;  BN = 1024; n0 = n0g; }
    else           { Cout = kvout; BN = 512;  n0 = n0g - 1024; }

    int lane = tid & 63, wave = tid >> 6;
    int r16 = lane & 15, quad = lane >> 4;
    int mb = (wave >> 1) * 64, nb = (wave & 1) * 64;
    int srow = tid >> 2, skg = (tid & 3) << 3;

#define STAGE_QKV(buf, k0)                                                         \
    do {                                                                           \
        GLL16(Ab + (size_t)(m0 + srow) * 1024 + (k0) + skg,      As[buf] + tid * 8);        \
        GLL16(Ab + (size_t)(m0 + srow + 64) * 1024 + (k0) + skg, As[buf] + (tid + 256) * 8);\
        GLL16(BT + (size_t)(n0g + srow) * 1024 + (k0) + skg,      Bs[buf] + tid * 8);       \
        GLL16(BT + (size_t)(n0g + srow + 64) * 1024 + (k0) + skg, Bs[buf] + (tid + 256) * 8);\
    } while (0)

    f32x4 acc[4][4];
#pragma unroll
    for (int mt = 0; mt < 4; mt++)
#pragma unroll
        for (int nt = 0; nt < 4; nt++) acc[mt][nt] = (f32x4){0.f, 0.f, 0.f, 0.f};

    STAGE_QKV(0, 0);
    __syncthreads();
    int cur = 0;
    for (int k0 = 0; k0 < 1024; k0 += 32) {
        if (k0 + 32 < 1024) STAGE_QKV(cur ^ 1, k0 + 32);
        bf16x8 af[4], bfr[4];
#pragma unroll
        for (int mt = 0; mt < 4; mt++)
            af[mt] = *(const bf16x8*)(As[cur] + (mb + mt * 16 + r16) * 32 + quad * 8);
#pragma unroll
        for (int nt = 0; nt < 4; nt++)
            bfr[nt] = *(const bf16x8*)(Bs[cur] + (nb + nt * 16 + r16) * 32 + quad * 8);
#pragma unroll
        for (int mt = 0; mt < 4; mt++)
#pragma unroll
            for (int nt = 0; nt < 4; nt++)
                acc[mt][nt] = __builtin_amdgcn_mfma_f32_16x16x32_bf16(af[mt], bfr[nt], acc[mt][nt], 0, 0, 0);
        __syncthreads();
        cur ^= 1;
    }
    if (ntile < 10) {
#pragma unroll
        for (int mt = 0; mt < 4; mt++)
#pragma unroll
            for (int nt = 0; nt < 4; nt++)
#pragma unroll
                for (int rg = 0; rg < 4; rg++) {
                    int row = m0 + mb + mt * 16 + quad * 4 + rg;
                    int col = n0 + nb + nt * 16 + r16;
                    Cout[(size_t)row * BN + col] = f2b(acc[mt][nt][rg]);
                }
    } else {
        // V-half: transposed store vt[b][kvh*64+d][s]
#pragma unroll
        for (int mt = 0; mt < 4; mt++)
#pragma unroll
            for (int nt = 0; nt < 4; nt++)
#pragma unroll
                for (int rg = 0; rg < 4; rg++) {
                    int row = m0 + mb + mt * 16 + quad * 4 + rg;
                    int col = n0 + nb + nt * 16 + r16;  // in [256,512)
                    int bb = row >> 10, s = row & 1023;
                    vtb[((size_t)bb << 18) + ((size_t)(col - 256) << 10) + s] =
                        f2b(acc[mt][nt][rg]);
                }
    }
#undef STAGE_QKV
}

// ---------------------------------------------------------------------------
// mgemm_proj2: BN=64 tiles -> 256 blocks (fills the GPU; was 128 blocks).
// ---------------------------------------------------------------------------
__global__ __launch_bounds__(256) void mgemm_proj2(const u16* __restrict__ Ab,
                                                   const u16* __restrict__ BT,
                                                   float* __restrict__ Cf) {
    __shared__ __align__(16) u16 As[2][128 * 32];
    __shared__ __align__(16) u16 Bs[2][64 * 32];
    int tid = threadIdx.x;
    int n0 = blockIdx.x * 64;
    int m0 = blockIdx.y * 128;

    int lane = tid & 63, wave = tid >> 6;
    int r16 = lane & 15, quad = lane >> 4;
    int mb = (wave >> 1) * 64, nb = (wave & 1) * 32;
    int srow = tid >> 2, skg = (tid & 3) << 3;

#define STAGE_PRJ(buf, k0)                                                         \
    do {                                                                           \
        GLL16(Ab + (size_t)(m0 + srow) * 1024 + (k0) + skg,      As[buf] + tid * 8);        \
        GLL16(Ab + (size_t)(m0 + srow + 64) * 1024 + (k0) + skg, As[buf] + (tid + 256) * 8);\
        GLL16(BT + (size_t)(n0 + srow) * 1024 + (k0) + skg,      Bs[buf] + tid * 8);        \
    } while (0)

    f32x4 acc[4][2];
#pragma unroll
    for (int mt = 0; mt < 4; mt++)
#pragma unroll
        for (int nt = 0; nt < 2; nt++) acc[mt][nt] = (f32x4){0.f, 0.f, 0.f, 0.f};

    STAGE_PRJ(0, 0);
    __syncthreads();
    int cur = 0;
    for (int k0 = 0; k0 < 1024; k0 += 32) {
        if (k0 + 32 < 1024) STAGE_PRJ(cur ^ 1, k0 + 32);
        bf16x8 af[4], bfr[2];
#pragma unroll
        for (int mt = 0; mt < 4; mt++)
            af[mt] = *(const bf16x8*)(As[cur] + (mb + mt * 16 + r16) * 32 + quad * 8);
#pragma unroll
        for (int nt = 0; nt < 2; nt++)
            bfr[nt] = *(const bf16x8*)(Bs[cur] + (nb + nt * 16 + r16) * 32 + quad * 8);
#pragma unroll
        for (int mt = 0; mt < 4; mt++)
#pragma unroll
            for (int nt = 0; nt < 2; nt++)
                acc[mt][nt] = __builtin_amdgcn_mfma_f32_16x16x32_bf16(af[mt], bfr[nt], acc[mt][nt], 0, 0, 0);
        __syncthreads();
        cur ^= 1;
    }
#pragma unroll
    for (int mt = 0; mt < 4; mt++)
#pragma unroll
        for (int nt = 0; nt < 2; nt++)
#pragma unroll
            for (int rg = 0; rg < 4; rg++) {
                int row = m0 + mb + mt * 16 + quad * 4 + rg;
                int col = n0 + nb + nt * 16 + r16;
                Cf[(size_t)row * 1024 + col] = acc[mt][nt][rg];
            }
#undef STAGE_PRJ
}

// ---------------------------------------------------------------------------
// mk_ta: MFMA time_att with fused rel-shift scatter (unchanged).
// ---------------------------------------------------------------------------
__global__ __launch_bounds__(256) void mk_ta(const u16* __restrict__ qb,
                                             const float* __restrict__ tkb,
                                             const float* __restrict__ bias,
                                             u16* __restrict__ tsb) {
    __shared__ __align__(16) u16 qs[128 * 72];
    __shared__ __align__(16) u16 tks[128 * 72];
    int tid = threadIdx.x;
    int t0 = blockIdx.x * 128;
    int h = blockIdx.y, b = blockIdx.z;
    int kvh = h >> 2;

#pragma unroll
    for (int it = 0; it < 4; it++) {
        int idx = tid + it * 256;
        int r = idx >> 3, dg = (idx & 7) << 3;
        uint4 u = *(const uint4*)(qb + ((size_t)(b * TT + t0 + r)) * EE + h * 64 + dg);
        u16 tmp[8]; *(uint4*)tmp = u;
        u16 outv[8];
#pragma unroll
        for (int j = 0; j < 8; j++) outv[j] = f2b(b2f(tmp[j]) + bias[EKVV + kvh * 64 + dg + j]);
        *(uint4*)(qs + r * 72 + dg) = *(uint4*)outv;
    }
#pragma unroll
    for (int it = 0; it < 4; it++) {
        int idx = tid + it * 256;
        int p = idx >> 3, dg = (idx & 7) << 3;
        const float* tp = tkb + p * EKVV + kvh * 64 + dg;
        float4 a0 = *(const float4*)(tp);
        float4 a1 = *(const float4*)(tp + 4);
        u16 outv[8] = {f2b(a0.x), f2b(a0.y), f2b(a0.z), f2b(a0.w),
                       f2b(a1.x), f2b(a1.y), f2b(a1.z), f2b(a1.w)};
        *(uint4*)(tks + p * 72 + dg) = *(uint4*)outv;
    }
    __syncthreads();

    int lane = tid & 63, wave = tid >> 6;
    int r16 = lane & 15, quad = lane >> 4;
    int mb = (wave >> 1) * 64, nb = (wave & 1) * 64;

    f32x4 acc[4][4];
#pragma unroll
    for (int mt = 0; mt < 4; mt++)
#pragma unroll
        for (int nt = 0; nt < 4; nt++) acc[mt][nt] = (f32x4){0.f, 0.f, 0.f, 0.f};

#pragma unroll
    for (int k0 = 0; k0 < 64; k0 += 32) {
        bf16x8 af[4], bfr[4];
#pragma unroll
        for (int mt = 0; mt < 4; mt++)
            af[mt] = *(const bf16x8*)(qs + (mb + mt * 16 + r16) * 72 + k0 + quad * 8);
#pragma unroll
        for (int nt = 0; nt < 4; nt++)
            bfr[nt] = *(const bf16x8*)(tks + (nb + nt * 16 + r16) * 72 + k0 + quad * 8);
#pragma unroll
        for (int mt = 0; mt < 4; mt++)
#pragma unroll
            for (int nt = 0; nt < 4; nt++)
                acc[mt][nt] = __builtin_amdgcn_mfma_f32_16x16x32_bf16(af[mt], bfr[nt], acc[mt][nt], 0, 0, 0);
    }

    size_t basebh = ((size_t)(b * HH + h)) * (TT * PP);
#pragma unroll
    for (int mt = 0; mt < 4; mt++)
#pragma unroll
        for (int nt = 0; nt < 4; nt++)
#pragma unroll
            for (int rg = 0; rg < 4; rg++) {
                int tp = t0 + mb + mt * 16 + quad * 4 + rg;
                int ppx = nb + nt * 16 + r16;
                int o = tp * PP + (tp >> 3) + 1 - PP + ppx;
                if (o >= 0) tsb[basebh + o] = f2b(acc[mt][nt][rg]);
            }
    if (blockIdx.x == 0 && tid < 127) {
        int tp = tid + 1;
        tsb[basebh + 1025 * tp - PP] = 0;
    }
}

// ---------------------------------------------------------------------------
// k_att4: big-tile MFMA flash attention.
// Round-2 restructure: (1) P gets its own LDS buffer (wave-private rows) ->
// barriers drop 4->2 per chunk; (2) T14 register prefetch of next chunk's
// V/ts/K, written to LDS after S1 -> global latency hides under compute;
// (3) hoisted mask constants.  LDS 71424 B -> still 2 blocks/CU.
// ---------------------------------------------------------------------------
__global__ __launch_bounds__(256) void k_att4(const u16* __restrict__ qb,
                                              const u16* __restrict__ kvb,
                                              const u16* __restrict__ vt,
                                              const u16* __restrict__ tsb,
                                              const float* __restrict__ ckb,
                                              const float* __restrict__ bias,
                                              u16* __restrict__ A2) {
    __shared__ __align__(16) char smem[71424];
    u16*   qg   = (u16*)(smem);              // [64][72] bf16 (q + gb)
    u16*   Kst  = (u16*)(smem + 9216);       // [128][72] bf16 K
    u16*   Pst  = (u16*)(smem + 27648);      // [64][136] bf16 P (wave-private rows)
    u16*   Vst  = (u16*)(smem + 45056);      // [64][138] bf16 (d-major)
    float* tsA  = (float*)(smem + 62720);    // [64][17] chunk time-shift
    float* csA  = (float*)(smem + 67072);    // [64][8] chan scores
    float* cks  = (float*)(smem + 69120);    // [8][64] ck rows
    float* cbmg = (float*)(smem + 71168);    // [64] cb - gb

    int tid = threadIdx.x;
    int lane = tid & 63, wave = tid >> 6;
    int r16 = lane & 15, quad = lane >> 4;
    int gx = blockIdx.x, h = blockIdx.y, b = blockIdx.z;
    int g = ((h ^ b) & 1) ? (15 - gx) : gx;   // balance co-resident pairs
    int kvh = h >> 2;
    int t0 = g * 64;
    int nch = (g + 2) >> 1;

    const u16* vbase = vt + ((size_t)(b * KVHH + kvh)) * DD * TT;
    size_t tsbase = ((size_t)(b * HH + h)) * (TT * PP);

    uint4 Vrg[4], Krg[4], Trg;
    bool pk_next = false;

    auto PRE = [&](int ci) {
        int c0p = ci * 128;
#pragma unroll
        for (int i = 0; i < 4; i++) {
            int idx = tid + i * 256;
            int d = idx >> 4, sg = (idx & 15) << 3;
            Vrg[i] = *(const uint4*)(vbase + (size_t)d * TT + c0p + sg);
        }
        if (tid < 128) {
            int row = tid >> 1, half = (tid & 1) << 3;
            Trg = *(const uint4*)(tsb + tsbase + (size_t)(t0 + row) * PP + (c0p >> 3) + half);
        }
        pk_next = (g == 15) || (c0p + 128 > g * 64 - 80);
        if (pk_next) {
#pragma unroll
            for (int i = 0; i < 4; i++) {
                int idx = tid + i * 256;
                int s = idx >> 3, dg = (idx & 7) << 3;
                Krg[i] = *(const uint4*)(kvb + ((size_t)(b * TT + c0p + s)) * (2 * EKVV) + kvh * 64 + dg);
            }
        }
    };

    PRE(0);  // chunk-0 loads fly during the prologue

#pragma unroll
    for (int i = 0; i < 2; i++) {
        int idx = tid + i * 256;
        int row = idx >> 3, dg = (idx & 7) << 3;
        uint4 u = *(const uint4*)(qb + ((size_t)(b * TT + t0 + row)) * EE + h * 64 + dg);
        u16 tmp[8]; *(uint4*)tmp = u;
        u16 o[8];
#pragma unroll
        for (int j = 0; j < 8; j++) o[j] = f2b(b2f(tmp[j]) + bias[kvh * 64 + dg + j]);
        *(uint4*)(qg + row * 72 + dg) = *(uint4*)o;
    }
    if (tid < 64) cbmg[tid] = bias[2 * EKVV + kvh * 64 + tid] - bias[kvh * 64 + tid];
#pragma unroll
    for (int i = 0; i < 2; i++) {
        int idx = tid + i * 256;
        cks[idx] = ckb[(idx >> 6) * EKVV + kvh * 64 + (idx & 63)];
    }
    __syncthreads();

    {
        int row = tid >> 2, cA = (tid & 3) << 1;
        int rm8 = row & 7;
        int d0 = rm8 - cA;       if (d0 < 0) d0 = -d0;
        int d1 = rm8 - (cA + 1); if (d1 < 0) d1 = -d1;
        const float* k0p = cks + (7 - d0) * 64;
        const float* k1p = cks + (7 - d1) * 64;
        float a0 = 0.f, a1 = 0.f;
#pragma unroll 8
        for (int d = 0; d < 64; d++) {
            float qv = b2f(qg[row * 72 + d]) + cbmg[d];
            a0 += qv * k0p[d];
            a1 += qv * k1p[d];
        }
        csA[row * 8 + cA] = a0;
        csA[row * 8 + cA + 1] = a1;
    }

    bf16x8 aq0 = *(const bf16x8*)(qg + (wave * 16 + r16) * 72 + quad * 8);
    bf16x8 aq1 = *(const bf16x8*)(qg + (wave * 16 + r16) * 72 + 32 + quad * 8);

    float m[4], l[4];
    f32x4 accv[4];
#pragma unroll
    for (int rg = 0; rg < 4; rg++) { m[rg] = -1.0e30f; l[rg] = 0.f; }
#pragma unroll
    for (int nt = 0; nt < 4; nt++) accv[nt] = (f32x4){0.f, 0.f, 0.f, 0.f};

    int rowbase = wave * 16 + quad * 4;
    int rpi[4];
#pragma unroll
    for (int rg = 0; rg < 4; rg++) rpi[rg] = (t0 + rowbase + rg) >> 3;

    for (int ci = 0; ci < nch; ci++) {
        int c0 = ci * 128;
        bool pk = pk_next;
        __syncthreads();  // S1: all waves done reading prev chunk's Vst/Kst/tsA
        {
#pragma unroll
            for (int i = 0; i < 4; i++) {
                int idx = tid + i * 256;
                int d = idx >> 4, sg = (idx & 15) << 3;
                *(uint4*)(Vst + d * 138 + sg) = Vrg[i];
            }
            if (tid < 128) {
                int row = tid >> 1, half = (tid & 1) << 3;
                u16 tmp[8]; *(uint4*)tmp = Trg;
#pragma unroll
                for (int j = 0; j < 8; j++) tsA[row * 17 + half + j] = b2f(tmp[j]);
            }
            if (pk) {
#pragma unroll
                for (int i = 0; i < 4; i++) {
                    int idx = tid + i * 256;
                    int s = idx >> 3, dg = (idx & 7) << 3;
                    *(uint4*)(Kst + s * 72 + dg) = Krg[i];
                }
            }
        }
        __syncthreads();  // S2: staged data visible
        if (ci + 1 < nch) PRE(ci + 1);  // next chunk's loads hide under compute

        f32x4 sc[8];
        if (pk) {
#pragma unroll
            for (int nt = 0; nt < 8; nt++) {
                const u16* kp = Kst + (nt * 16 + r16) * 72 + quad * 8;
                bf16x8 b0 = *(const bf16x8*)(kp);
                bf16x8 b1 = *(const bf16x8*)(kp + 32);
                f32x4 a = {0.f, 0.f, 0.f, 0.f};
                a = __builtin_amdgcn_mfma_f32_16x16x32_bf16(aq0, b0, a, 0, 0, 0);
                a = __builtin_amdgcn_mfma_f32_16x16x32_bf16(aq1, b1, a, 0, 0, 0);
                sc[nt] = a;
            }
        } else {
#pragma unroll
            for (int nt = 0; nt < 8; nt++) sc[nt] = (f32x4){0.f, 0.f, 0.f, 0.f};
        }

        float csr[4];
#pragma unroll
        for (int rg = 0; rg < 4; rg++) csr[rg] = csA[(rowbase + rg) * 8 + (r16 & 7)];
#pragma unroll
        for (int nt = 0; nt < 8; nt++) {
            int spi = (c0 + nt * 16 + r16) >> 3;
#pragma unroll
            for (int rg = 0; rg < 4; rg++) {
                float ts = tsA[(rowbase + rg) * 17 + 2 * nt + (r16 >> 3)];
                bool win = (rpi[rg] == 127) || (rpi[rg] - spi <= 10);
                float scv = ((win ? sc[nt][rg] : 0.f) + ts + csr[rg]) * 0.125f;
                sc[nt][rg] = (spi <= rpi[rg]) ? scv : -1.0e30f;
            }
        }

        float cm[4], alpha[4], psum[4];
#pragma unroll
        for (int rg = 0; rg < 4; rg++) {
            float v = sc[0][rg];
#pragma unroll
            for (int nt = 1; nt < 8; nt++) v = fmaxf(v, sc[nt][rg]);
#pragma unroll
            for (int off = 1; off < 16; off <<= 1) v = fmaxf(v, __shfl_xor(v, off));
            float mn = fmaxf(m[rg], v);
            alpha[rg] = __expf(m[rg] - mn);
            m[rg] = mn;
            cm[rg] = mn;
        }
#pragma unroll
        for (int rg = 0; rg < 4; rg++) psum[rg] = 0.f;
#pragma unroll
        for (int nt = 0; nt < 8; nt++)
#pragma unroll
            for (int rg = 0; rg < 4; rg++) {
                float e = __expf(sc[nt][rg] - cm[rg]);
                sc[nt][rg] = e;
                psum[rg] += e;
            }
#pragma unroll
        for (int rg = 0; rg < 4; rg++) {
#pragma unroll
            for (int off = 1; off < 16; off <<= 1) psum[rg] += __shfl_xor(psum[rg], off);
            l[rg] = l[rg] * alpha[rg] + psum[rg];
        }
#pragma unroll
        for (int nt = 0; nt < 4; nt++)
#pragma unroll
            for (int rg = 0; rg < 4; rg++) accv[nt][rg] *= alpha[rg];

        // P store: wave-private rows -> no barrier needed around it
#pragma unroll
        for (int nt = 0; nt < 8; nt++)
#pragma unroll
            for (int rg = 0; rg < 4; rg++)
                Pst[(rowbase + rg) * 136 + nt * 16 + r16] = f2b(sc[nt][rg]);
        asm volatile("s_waitcnt lgkmcnt(0)" ::: "memory");

#pragma unroll
        for (int ks = 0; ks < 4; ks++) {
            bf16x8 ap = *(const bf16x8*)(Pst + (wave * 16 + r16) * 136 + ks * 32 + quad * 8);
#pragma unroll
            for (int nt = 0; nt < 4; nt++) {
                bf16x8 bv = *(const bf16x8*)(Vst + (nt * 16 + r16) * 138 + ks * 32 + quad * 8);
                accv[nt] = __builtin_amdgcn_mfma_f32_16x16x32_bf16(ap, bv, accv[nt], 0, 0, 0);
            }
        }
    }

#pragma unroll
    for (int nt = 0; nt < 4; nt++)
#pragma unroll
        for (int rg = 0; rg < 4; rg++) {
            int rt = t0 + rowbase + rg;
            A2[((size_t)(b * TT + rt)) * EE + h * 64 + nt * 16 + r16] =
                f2b(accv[nt][rg] / l[rg]);
        }
}

extern "C" void kernel_launch(void* const* d_in, const int* in_sizes, int n_in,
                              void* d_out, int out_size, void* d_ws, size_t ws_size,
                              hipStream_t stream) {
    const float* hidden = (const float*)d_in[0];
    const float* pos    = (const float*)d_in[1];
    const float* chan   = (const float*)d_in[2];
    const float* Wq     = (const float*)d_in[3];
    const float* Wkv    = (const float*)d_in[4];
    const float* Wpos   = (const float*)d_in[5];
    const float* Wchan  = (const float*)d_in[6];
    const float* Wproj  = (const float*)d_in[7];
    const float* bias   = (const float*)d_in[8];

    // workspace carve: ~28.2 MB total
    u16* qb    = (u16*)d_ws;               // 2,097,152 u16 (4 MB)
    u16* kvb   = qb + 2097152;             // 1,048,576 u16 (2 MB)
    u16* tsb   = kvb + 1048576;            // 4,194,304 u16 (8 MB)
    u16* A2    = tsb + 4194304;            // 2,097,152 u16 (4 MB)
    u16* vt    = A2 + 2097152;             //   524,288 u16 (1 MB)
    u16* hb    = vt + 524288;              // 2,097,152 u16 (4 MB) hidden bf16
    u16* btq   = hb + 2097152;             // 1,572,864 u16 (3 MB) [Wq;Wkv]^T bf16
    u16* btp   = btq + 1572864;            // 1,048,576 u16 (2 MB) Wproj^T bf16
    float* tkb = (float*)(btp + 1048576);  //    32,768 f32 (128 KB)
    float* ckb = tkb + 32768;              //     2,048 f32 (8 KB)

    dim3 blk(256);
    // one-time bf16 conversions + weight transposes + tkb/ckb zero
    k_prep<<<3584, blk, 0, stream>>>(hidden, Wq, Wkv, Wproj, hb, btq, btp, tkb);
    // tiny projections via split-K (pos + chan in one dispatch)
    sgemm_sk<<<dim3(12, 8), blk, 0, stream>>>(pos, Wpos, chan, Wchan, tkb, ckb);
    // fused q/kv projection via MFMA (V-half written transposed to vt)
    mgemm_qkv2<<<dim3(12, 16), blk, 0, stream>>>(hb, btq, qb, kvb, vt);
    // MFMA time_att with fused rel-shift scatter -> tsb (bf16)
    mk_ta<<<dim3(8, 16, 2), blk, 0, stream>>>(qb, tkb, bias, tsb);
    // big-tile MFMA flash attention -> A2 (bf16)
    k_att4<<<dim3(16, 16, 2), blk, 0, stream>>>(qb, kvb, vt, tsb, ckb, bias, A2);
    // output projection via MFMA -> fp32 d_out
    mgemm_proj2<<<dim3(16, 16), blk, 0, stream>>>(A2, btp, (float*)d_out);
}

// Round 3
// 188.588 us; speedup vs baseline: 1.1062x; 1.1062x over previous
//
#include <hip/hip_runtime.h>
#include <hip/hip_bf16.h>

#define BB 2
#define PP 128
#define CC 8
#define EE 1024
#define HH 16
#define KVHH 4
#define DD 64
#define TT 1024
#define EKVV 256

typedef unsigned short u16;
typedef unsigned int u32;
typedef __attribute__((ext_vector_type(8))) short bf16x8;
typedef __attribute__((ext_vector_type(4))) float f32x4;

__device__ __forceinline__ float b2f(u16 u) {
    u32 x = ((u32)u) << 16;
    return __uint_as_float(x);
}
__device__ __forceinline__ u16 f2b(float f) {
    u32 x = __float_as_uint(f);
    u32 r = (x + 0x7FFFu + ((x >> 16) & 1u)) >> 16;
    return (u16)r;
}

// async global->LDS 16B (wave-uniform LDS base + lane*16 layout required)
#define GLL16(gp, lp)                                                          \
    __builtin_amdgcn_global_load_lds(                                          \
        (__attribute__((address_space(1))) void*)(gp),                         \
        (__attribute__((address_space(3))) void*)(lp), 16, 0, 0)

// ---------------------------------------------------------------------------
// k_prep: one-time conversions + tkb/ckb zeroing.
// ---------------------------------------------------------------------------
__global__ __launch_bounds__(256) void k_prep(const float* __restrict__ hidden,
                                              const float* __restrict__ Wq,
                                              const float* __restrict__ Wkv,
                                              const float* __restrict__ Wproj,
                                              u16* __restrict__ hb,
                                              u16* __restrict__ btq,
                                              u16* __restrict__ btp,
                                              float* __restrict__ tkb) {
    __shared__ float ts[32][33];
    int bid = blockIdx.x;
    int tid = threadIdx.x;
    if (bid < 1024) {
        if (bid < 34)  // zero tkb(32768)+ckb(2048) = 8704 float4
            ((float4*)tkb)[bid * 256 + tid] = make_float4(0.f, 0.f, 0.f, 0.f);
        int base = (bid * 256 + tid) * 8;
        float4 a0 = *(const float4*)(hidden + base);
        float4 a1 = *(const float4*)(hidden + base + 4);
        u16 o[8] = {f2b(a0.x), f2b(a0.y), f2b(a0.z), f2b(a0.w),
                    f2b(a1.x), f2b(a1.y), f2b(a1.z), f2b(a1.w)};
        *(uint4*)(hb + base) = *(uint4*)o;
        return;
    }
    bid -= 1024;
    const float* W;
    u16* out;
    int N, tk, tn;
    if (bid < 1024) {
        W = Wq; out = btq; N = 1024; tk = bid >> 5; tn = bid & 31;
    } else if (bid < 1536) {
        int b2 = bid - 1024;
        W = Wkv; out = btq + 1024 * 1024; N = 512; tk = b2 >> 4; tn = b2 & 15;
    } else {
        int b2 = bid - 1536;
        W = Wproj; out = btp; N = 1024; tk = b2 >> 5; tn = b2 & 31;
    }
    int r = tid >> 3, c4 = (tid & 7) << 2;
    float4 v = *(const float4*)(W + (size_t)(tk * 32 + r) * N + tn * 32 + c4);
    ts[r][c4 + 0] = v.x;
    ts[r][c4 + 1] = v.y;
    ts[r][c4 + 2] = v.z;
    ts[r][c4 + 3] = v.w;
    __syncthreads();
    u16 o[4] = {f2b(ts[c4 + 0][r]), f2b(ts[c4 + 1][r]),
                f2b(ts[c4 + 2][r]), f2b(ts[c4 + 3][r])};
    *(ushort4*)(out + (size_t)(tn * 32 + r) * 1024 + tk * 32 + c4) = *(ushort4*)o;
}

// ---------------------------------------------------------------------------
// sgemm_sk: split-K GEMM for the two tiny projections (unchanged).
// ---------------------------------------------------------------------------
__global__ __launch_bounds__(256) void sgemm_sk(const float* __restrict__ pos,
                                                const float* __restrict__ Wpos,
                                                const float* __restrict__ chan,
                                                const float* __restrict__ Wchan,
                                                float* __restrict__ tkb,
                                                float* __restrict__ ckb) {
    __shared__ float As[16][68];
    __shared__ float Bs[16][68];
    int tile = blockIdx.x;
    const float* A; const float* B; float* C; int M, m0, n0;
    if (tile < 8) { A = pos;  B = Wpos;  C = tkb; M = 128; m0 = (tile >> 2) * 64; n0 = (tile & 3) * 64; }
    else          { A = chan; B = Wchan; C = ckb; M = 8;   m0 = 0;               n0 = (tile - 8) * 64; }
    int kbase = blockIdx.y * 128;

    int tid = threadIdx.x;
    int tx = tid & 15, ty = tid >> 4;
    float acc[4][4];
#pragma unroll
    for (int r = 0; r < 4; r++)
#pragma unroll
        for (int c = 0; c < 4; c++) acc[r][c] = 0.f;

    int am = tid >> 2, ak = (tid & 3) << 2;
    int bk = tid >> 4, bn = (tid & 15) << 2;

    for (int k0 = kbase; k0 < kbase + 128; k0 += 16) {
        int row = m0 + am;
        float4 av;
        if (row < M) av = *reinterpret_cast<const float4*>(A + (size_t)row * 1024 + k0 + ak);
        else av = make_float4(0.f, 0.f, 0.f, 0.f);
        As[ak + 0][am] = av.x;
        As[ak + 1][am] = av.y;
        As[ak + 2][am] = av.z;
        As[ak + 3][am] = av.w;
        float4 bv = *reinterpret_cast<const float4*>(B + (size_t)(k0 + bk) * 256 + n0 + bn);
        Bs[bk][bn + 0] = bv.x;
        Bs[bk][bn + 1] = bv.y;
        Bs[bk][bn + 2] = bv.z;
        Bs[bk][bn + 3] = bv.w;
        __syncthreads();
#pragma unroll
        for (int kk = 0; kk < 16; kk++) {
            float4 a4 = *reinterpret_cast<const float4*>(&As[kk][ty << 2]);
            float4 b4 = *reinterpret_cast<const float4*>(&Bs[kk][tx << 2]);
            acc[0][0] += a4.x * b4.x; acc[0][1] += a4.x * b4.y; acc[0][2] += a4.x * b4.z; acc[0][3] += a4.x * b4.w;
            acc[1][0] += a4.y * b4.x; acc[1][1] += a4.y * b4.y; acc[1][2] += a4.y * b4.z; acc[1][3] += a4.y * b4.w;
            acc[2][0] += a4.z * b4.x; acc[2][1] += a4.z * b4.y; acc[2][2] += a4.z * b4.z; acc[2][3] += a4.z * b4.w;
            acc[3][0] += a4.w * b4.x; acc[3][1] += a4.w * b4.y; acc[3][2] += a4.w * b4.z; acc[3][3] += a4.w * b4.w;
        }
        __syncthreads();
    }
#pragma unroll
    for (int r = 0; r < 4; r++) {
        int row = m0 + (ty << 2) + r;
        if (row < M) {
#pragma unroll
            for (int c = 0; c < 4; c++) {
                int col = n0 + (tx << 2) + c;
                atomicAdd(&C[(size_t)row * 256 + col], acc[r][c]);
            }
        }
    }
}

// ---------------------------------------------------------------------------
// mgemm_qkv2: m97-structure bf16 GEMM (global_load_lds + 2-phase dbuf).
// V-half output (ntile 10,11) written TRANSPOSED straight to vt.
// ---------------------------------------------------------------------------
__global__ __launch_bounds__(256) void mgemm_qkv2(const u16* __restrict__ Ab,
                                                  const u16* __restrict__ BT,
                                                  u16* __restrict__ qout,
                                                  u16* __restrict__ kvout,
                                                  u16* __restrict__ vtb) {
    __shared__ __align__(16) u16 As[2][128 * 32];
    __shared__ __align__(16) u16 Bs[2][128 * 32];
    int tid = threadIdx.x;
    int ntile = blockIdx.x;
    int m0 = blockIdx.y * 128;
    int n0g = ntile * 128;
    u16* Cout; int BN, n0;
    if (ntile < 8) { Cout = qout;  BN = 1024; n0 = n0g; }
    else           { Cout = kvout; BN = 512;  n0 = n0g - 1024; }

    int lane = tid & 63, wave = tid >> 6;
    int r16 = lane & 15, quad = lane >> 4;
    int mb = (wave >> 1) * 64, nb = (wave & 1) * 64;
    int srow = tid >> 2, skg = (tid & 3) << 3;

#define STAGE_QKV(buf, k0)                                                         \
    do {                                                                           \
        GLL16(Ab + (size_t)(m0 + srow) * 1024 + (k0) + skg,      As[buf] + tid * 8);        \
        GLL16(Ab + (size_t)(m0 + srow + 64) * 1024 + (k0) + skg, As[buf] + (tid + 256) * 8);\
        GLL16(BT + (size_t)(n0g + srow) * 1024 + (k0) + skg,      Bs[buf] + tid * 8);       \
        GLL16(BT + (size_t)(n0g + srow + 64) * 1024 + (k0) + skg, Bs[buf] + (tid + 256) * 8);\
    } while (0)

    f32x4 acc[4][4];
#pragma unroll
    for (int mt = 0; mt < 4; mt++)
#pragma unroll
        for (int nt = 0; nt < 4; nt++) acc[mt][nt] = (f32x4){0.f, 0.f, 0.f, 0.f};

    STAGE_QKV(0, 0);
    __syncthreads();
    int cur = 0;
    for (int k0 = 0; k0 < 1024; k0 += 32) {
        if (k0 + 32 < 1024) STAGE_QKV(cur ^ 1, k0 + 32);
        bf16x8 af[4], bfr[4];
#pragma unroll
        for (int mt = 0; mt < 4; mt++)
            af[mt] = *(const bf16x8*)(As[cur] + (mb + mt * 16 + r16) * 32 + quad * 8);
#pragma unroll
        for (int nt = 0; nt < 4; nt++)
            bfr[nt] = *(const bf16x8*)(Bs[cur] + (nb + nt * 16 + r16) * 32 + quad * 8);
#pragma unroll
        for (int mt = 0; mt < 4; mt++)
#pragma unroll
            for (int nt = 0; nt < 4; nt++)
                acc[mt][nt] = __builtin_amdgcn_mfma_f32_16x16x32_bf16(af[mt], bfr[nt], acc[mt][nt], 0, 0, 0);
        __syncthreads();
        cur ^= 1;
    }
    if (ntile < 10) {
#pragma unroll
        for (int mt = 0; mt < 4; mt++)
#pragma unroll
            for (int nt = 0; nt < 4; nt++)
#pragma unroll
                for (int rg = 0; rg < 4; rg++) {
                    int row = m0 + mb + mt * 16 + quad * 4 + rg;
                    int col = n0 + nb + nt * 16 + r16;
                    Cout[(size_t)row * BN + col] = f2b(acc[mt][nt][rg]);
                }
    } else {
        // V-half: transposed store vt[b][kvh*64+d][s]
#pragma unroll
        for (int mt = 0; mt < 4; mt++)
#pragma unroll
            for (int nt = 0; nt < 4; nt++)
#pragma unroll
                for (int rg = 0; rg < 4; rg++) {
                    int row = m0 + mb + mt * 16 + quad * 4 + rg;
                    int col = n0 + nb + nt * 16 + r16;  // in [256,512)
                    int bb = row >> 10, s = row & 1023;
                    vtb[((size_t)bb << 18) + ((size_t)(col - 256) << 10) + s] =
                        f2b(acc[mt][nt][rg]);
                }
    }
#undef STAGE_QKV
}

// ---------------------------------------------------------------------------
// mgemm_proj2: BN=64 tiles -> 256 blocks.
// ---------------------------------------------------------------------------
__global__ __launch_bounds__(256) void mgemm_proj2(const u16* __restrict__ Ab,
                                                   const u16* __restrict__ BT,
                                                   float* __restrict__ Cf) {
    __shared__ __align__(16) u16 As[2][128 * 32];
    __shared__ __align__(16) u16 Bs[2][64 * 32];
    int tid = threadIdx.x;
    int n0 = blockIdx.x * 64;
    int m0 = blockIdx.y * 128;

    int lane = tid & 63, wave = tid >> 6;
    int r16 = lane & 15, quad = lane >> 4;
    int mb = (wave >> 1) * 64, nb = (wave & 1) * 32;
    int srow = tid >> 2, skg = (tid & 3) << 3;

#define STAGE_PRJ(buf, k0)                                                         \
    do {                                                                           \
        GLL16(Ab + (size_t)(m0 + srow) * 1024 + (k0) + skg,      As[buf] + tid * 8);        \
        GLL16(Ab + (size_t)(m0 + srow + 64) * 1024 + (k0) + skg, As[buf] + (tid + 256) * 8);\
        GLL16(BT + (size_t)(n0 + srow) * 1024 + (k0) + skg,      Bs[buf] + tid * 8);        \
    } while (0)

    f32x4 acc[4][2];
#pragma unroll
    for (int mt = 0; mt < 4; mt++)
#pragma unroll
        for (int nt = 0; nt < 2; nt++) acc[mt][nt] = (f32x4){0.f, 0.f, 0.f, 0.f};

    STAGE_PRJ(0, 0);
    __syncthreads();
    int cur = 0;
    for (int k0 = 0; k0 < 1024; k0 += 32) {
        if (k0 + 32 < 1024) STAGE_PRJ(cur ^ 1, k0 + 32);
        bf16x8 af[4], bfr[2];
#pragma unroll
        for (int mt = 0; mt < 4; mt++)
            af[mt] = *(const bf16x8*)(As[cur] + (mb + mt * 16 + r16) * 32 + quad * 8);
#pragma unroll
        for (int nt = 0; nt < 2; nt++)
            bfr[nt] = *(const bf16x8*)(Bs[cur] + (nb + nt * 16 + r16) * 32 + quad * 8);
#pragma unroll
        for (int mt = 0; mt < 4; mt++)
#pragma unroll
            for (int nt = 0; nt < 2; nt++)
                acc[mt][nt] = __builtin_amdgcn_mfma_f32_16x16x32_bf16(af[mt], bfr[nt], acc[mt][nt], 0, 0, 0);
        __syncthreads();
        cur ^= 1;
    }
#pragma unroll
    for (int mt = 0; mt < 4; mt++)
#pragma unroll
        for (int nt = 0; nt < 2; nt++)
#pragma unroll
            for (int rg = 0; rg < 4; rg++) {
                int row = m0 + mb + mt * 16 + quad * 4 + rg;
                int col = n0 + nb + nt * 16 + r16;
                Cf[(size_t)row * 1024 + col] = acc[mt][nt][rg];
            }
#undef STAGE_PRJ
}

// ---------------------------------------------------------------------------
// k_att4: big-tile MFMA flash attention.
// Round-3: (1) spill fix — prefetch in NAMED uint4 regs, no lambda/arrays;
// (2) mk_ta fused: prologue computes ta = (q+tb)*tk^T into LDS (reusing qg's
// region), rel-shift becomes an index shift at read (ts[row][spi] =
// ta[row][spi+127-rpi]; out-of-range only where mask kills the value).
// LDS 75520 B -> 2 blocks/CU.
// ---------------------------------------------------------------------------
__global__ __launch_bounds__(256, 2) void k_att4(const u16* __restrict__ qb,
                                                 const u16* __restrict__ kvb,
                                                 const u16* __restrict__ vt,
                                                 const float* __restrict__ tkb,
                                                 const float* __restrict__ ckb,
                                                 const float* __restrict__ bias,
                                                 u16* __restrict__ A2) {
    __shared__ __align__(16) char smem[75520];
    u16*   taS  = (u16*)(smem);              // [64][136] bf16 ta (prologue: qg [64][72])
    u16*   qg   = (u16*)(smem);              // [64][72] bf16 (q + gb), prologue only
    u16*   Kst  = (u16*)(smem + 17408);      // [128][72] bf16 K (prologue: tk)
    u16*   Pst  = (u16*)(smem + 35840);      // [64][136] bf16 P (wave-private rows)
    u16*   Vst  = (u16*)(smem + 53248);      // [64][138] bf16 V (d-major)
    float* csA  = (float*)(smem + 70912);    // [64][8] chan scores
    float* cks  = (float*)(smem + 72960);    // [8][64] ck rows
    float* cbmg = (float*)(smem + 75008);    // [64] cb - gb
    float* tbv  = (float*)(smem + 75264);    // [64] tb

    int tid = threadIdx.x;
    int lane = tid & 63, wave = tid >> 6;
    int r16 = lane & 15, quad = lane >> 4;
    int gx = blockIdx.x, h = blockIdx.y, b = blockIdx.z;
    int g = ((h ^ b) & 1) ? (15 - gx) : gx;   // balance co-resident pairs
    int kvh = h >> 2;
    int t0 = g * 64;
    int nch = (g + 2) >> 1;

    // per-thread staging bases (element i differs by a constant stride only)
    const u16* vptr = vt + ((size_t)(b * KVHH + kvh)) * DD * TT
                    + (size_t)(tid >> 4) * TT + ((tid & 15) << 3);
    const u16* kptr = kvb + ((size_t)(b * TT) + (tid >> 3)) * (2 * EKVV)
                    + kvh * 64 + ((tid & 7) << 3);

    uint4 V0g, V1g, V2g, V3g, K0g, K1g, K2g, K3g;
    bool pk_next;

#define PRE(c0p)                                                               \
    do {                                                                       \
        V0g = *(const uint4*)(vptr + (c0p));                                   \
        V1g = *(const uint4*)(vptr + 16 * TT + (c0p));                         \
        V2g = *(const uint4*)(vptr + 32 * TT + (c0p));                         \
        V3g = *(const uint4*)(vptr + 48 * TT + (c0p));                         \
        pk_next = (g == 15) || ((c0p) + 128 > g * 64 - 80);                    \
        if (pk_next) {                                                         \
            const u16* kp_ = kptr + (size_t)(c0p) * (2 * EKVV);                \
            K0g = *(const uint4*)(kp_);                                        \
            K1g = *(const uint4*)(kp_ + 32 * 2 * EKVV);                        \
            K2g = *(const uint4*)(kp_ + 64 * 2 * EKVV);                        \
            K3g = *(const uint4*)(kp_ + 96 * 2 * EKVV);                        \
        }                                                                      \
    } while (0)

    PRE(0);  // chunk-0 loads fly during the whole prologue

    // ---- prologue staging: qg (q+gb), cks, cbmg, tbv ----
#pragma unroll
    for (int i = 0; i < 2; i++) {
        int idx = tid + i * 256;
        int row = idx >> 3, dg = (idx & 7) << 3;
        uint4 u = *(const uint4*)(qb + ((size_t)(b * TT + t0 + row)) * EE + h * 64 + dg);
        u16 tmp[8]; *(uint4*)tmp = u;
        u16 o[8];
#pragma unroll
        for (int j = 0; j < 8; j++) o[j] = f2b(b2f(tmp[j]) + bias[kvh * 64 + dg + j]);
        *(uint4*)(qg + row * 72 + dg) = *(uint4*)o;
    }
    if (tid < 64) {
        cbmg[tid] = bias[2 * EKVV + kvh * 64 + tid] - bias[kvh * 64 + tid];
        tbv[tid]  = bias[EKVV + kvh * 64 + tid];
    }
#pragma unroll
    for (int i = 0; i < 2; i++) {
        int idx = tid + i * 256;
        cks[idx] = ckb[(idx >> 6) * EKVV + kvh * 64 + (idx & 63)];
    }
    __syncthreads();  // B1

    // ---- channel scores ----
    {
        int row = tid >> 2, cA = (tid & 3) << 1;
        int rm8 = row & 7;
        int d0 = rm8 - cA;       if (d0 < 0) d0 = -d0;
        int d1 = rm8 - (cA + 1); if (d1 < 0) d1 = -d1;
        const float* k0p = cks + (7 - d0) * 64;
        const float* k1p = cks + (7 - d1) * 64;
        float a0 = 0.f, a1 = 0.f;
#pragma unroll 8
        for (int d = 0; d < 64; d++) {
            float qv = b2f(qg[row * 72 + d]) + cbmg[d];
            a0 += qv * k0p[d];
            a1 += qv * k1p[d];
        }
        csA[row * 8 + cA] = a0;
        csA[row * 8 + cA + 1] = a1;
    }

    // ---- q fragments: q+gb (from qg) and q+tb (fresh from qb + tbv) ----
    bf16x8 aq0 = *(const bf16x8*)(qg + (wave * 16 + r16) * 72 + quad * 8);
    bf16x8 aq1 = *(const bf16x8*)(qg + (wave * 16 + r16) * 72 + 32 + quad * 8);
    bf16x8 aqt0, aqt1;
    {
        const u16* qrow = qb + ((size_t)(b * TT + t0 + wave * 16 + r16)) * EE + h * 64;
        uint4 u0 = *(const uint4*)(qrow + quad * 8);
        uint4 u1 = *(const uint4*)(qrow + 32 + quad * 8);
        u16 t0v[8], t1v[8]; *(uint4*)t0v = u0; *(uint4*)t1v = u1;
        u16 o0[8], o1[8];
#pragma unroll
        for (int j = 0; j < 8; j++) {
            o0[j] = f2b(b2f(t0v[j]) + tbv[quad * 8 + j]);
            o1[j] = f2b(b2f(t1v[j]) + tbv[32 + quad * 8 + j]);
        }
        aqt0 = *(bf16x8*)o0;
        aqt1 = *(bf16x8*)o1;
    }

    // ---- stage tk -> Kst (bf16 [128][72]) ----
#pragma unroll
    for (int i = 0; i < 4; i++) {
        int idx = tid + i * 256;
        int p = idx >> 3, dg = (idx & 7) << 3;
        const float* tp = tkb + p * EKVV + kvh * 64 + dg;
        float4 a0 = *(const float4*)(tp);
        float4 a1 = *(const float4*)(tp + 4);
        u16 o[8] = {f2b(a0.x), f2b(a0.y), f2b(a0.z), f2b(a0.w),
                    f2b(a1.x), f2b(a1.y), f2b(a1.z), f2b(a1.w)};
        *(uint4*)(Kst + p * 72 + dg) = *(uint4*)o;
    }
    __syncthreads();  // B2: qg reads done; tk visible

    // ---- ta = (q+tb) * tk^T, rows = this wave's 16 rows, bf16 into taS ----
#pragma unroll
    for (int nt = 0; nt < 8; nt++) {
        const u16* kp = Kst + (nt * 16 + r16) * 72 + quad * 8;
        bf16x8 b0 = *(const bf16x8*)(kp);
        bf16x8 b1 = *(const bf16x8*)(kp + 32);
        f32x4 a = {0.f, 0.f, 0.f, 0.f};
        a = __builtin_amdgcn_mfma_f32_16x16x32_bf16(aqt0, b0, a, 0, 0, 0);
        a = __builtin_amdgcn_mfma_f32_16x16x32_bf16(aqt1, b1, a, 0, 0, 0);
#pragma unroll
        for (int rg = 0; rg < 4; rg++)
            taS[(wave * 16 + quad * 4 + rg) * 136 + nt * 16 + r16] = f2b(a[rg]);
    }

    float m[4], l[4];
    f32x4 accv[4];
#pragma unroll
    for (int rg = 0; rg < 4; rg++) { m[rg] = -1.0e30f; l[rg] = 0.f; }
#pragma unroll
    for (int nt = 0; nt < 4; nt++) accv[nt] = (f32x4){0.f, 0.f, 0.f, 0.f};

    int rowbase = wave * 16 + quad * 4;
    int rpi[4];
#pragma unroll
    for (int rg = 0; rg < 4; rg++) rpi[rg] = (t0 + rowbase + rg) >> 3;

    for (int ci = 0; ci < nch; ci++) {
        int c0 = ci * 128;
        bool pk = pk_next;
        __syncthreads();  // S1: all waves done with prev chunk LDS + prologue Kst reads
        {
            u16* vw = Vst + (tid >> 4) * 138 + ((tid & 15) << 3);
            *(uint4*)(vw)            = V0g;
            *(uint4*)(vw + 16 * 138) = V1g;
            *(uint4*)(vw + 32 * 138) = V2g;
            *(uint4*)(vw + 48 * 138) = V3g;
            if (pk) {
                u16* kw = Kst + (tid >> 3) * 72 + ((tid & 7) << 3);
                *(uint4*)(kw)           = K0g;
                *(uint4*)(kw + 32 * 72) = K1g;
                *(uint4*)(kw + 64 * 72) = K2g;
                *(uint4*)(kw + 96 * 72) = K3g;
            }
        }
        if (ci + 1 < nch) PRE((ci + 1) * 128);  // next chunk flies under compute
        __syncthreads();  // S2: staged data visible

        f32x4 sc[8];
        if (pk) {
#pragma unroll
            for (int nt = 0; nt < 8; nt++) {
                const u16* kp = Kst + (nt * 16 + r16) * 72 + quad * 8;
                bf16x8 b0 = *(const bf16x8*)(kp);
                bf16x8 b1 = *(const bf16x8*)(kp + 32);
                f32x4 a = {0.f, 0.f, 0.f, 0.f};
                a = __builtin_amdgcn_mfma_f32_16x16x32_bf16(aq0, b0, a, 0, 0, 0);
                a = __builtin_amdgcn_mfma_f32_16x16x32_bf16(aq1, b1, a, 0, 0, 0);
                sc[nt] = a;
            }
        } else {
#pragma unroll
            for (int nt = 0; nt < 8; nt++) sc[nt] = (f32x4){0.f, 0.f, 0.f, 0.f};
        }

        float csr[4];
#pragma unroll
        for (int rg = 0; rg < 4; rg++) csr[rg] = csA[(rowbase + rg) * 8 + (r16 & 7)];
#pragma unroll
        for (int nt = 0; nt < 8; nt++) {
            int spi = (c0 + nt * 16 + r16) >> 3;
#pragma unroll
            for (int rg = 0; rg < 4; rg++) {
                // rel-shift read: ts[row][spi] = ta[row][spi+127-rpi].
                // spi>rpi reads stray bytes (still inside smem) but is masked.
                int cp = spi + 127 - rpi[rg];
                float ts = b2f(taS[(rowbase + rg) * 136 + cp]);
                bool win = (rpi[rg] == 127) || (rpi[rg] - spi <= 10);
                float scv = ((win ? sc[nt][rg] : 0.f) + ts + csr[rg]) * 0.125f;
                sc[nt][rg] = (spi <= rpi[rg]) ? scv : -1.0e30f;
            }
        }

        float cm[4], alpha[4], psum[4];
#pragma unroll
        for (int rg = 0; rg < 4; rg++) {
            float v = sc[0][rg];
#pragma unroll
            for (int nt = 1; nt < 8; nt++) v = fmaxf(v, sc[nt][rg]);
#pragma unroll
            for (int off = 1; off < 16; off <<= 1) v = fmaxf(v, __shfl_xor(v, off));
            float mn = fmaxf(m[rg], v);
            alpha[rg] = __expf(m[rg] - mn);
            m[rg] = mn;
            cm[rg] = mn;
        }
#pragma unroll
        for (int rg = 0; rg < 4; rg++) psum[rg] = 0.f;
#pragma unroll
        for (int nt = 0; nt < 8; nt++)
#pragma unroll
            for (int rg = 0; rg < 4; rg++) {
                float e = __expf(sc[nt][rg] - cm[rg]);
                sc[nt][rg] = e;
                psum[rg] += e;
            }
#pragma unroll
        for (int rg = 0; rg < 4; rg++) {
#pragma unroll
            for (int off = 1; off < 16; off <<= 1) psum[rg] += __shfl_xor(psum[rg], off);
            l[rg] = l[rg] * alpha[rg] + psum[rg];
        }
#pragma unroll
        for (int nt = 0; nt < 4; nt++)
#pragma unroll
            for (int rg = 0; rg < 4; rg++) accv[nt][rg] *= alpha[rg];

        // P store: wave-private rows -> no barrier needed around it
#pragma unroll
        for (int nt = 0; nt < 8; nt++)
#pragma unroll
            for (int rg = 0; rg < 4; rg++)
                Pst[(rowbase + rg) * 136 + nt * 16 + r16] = f2b(sc[nt][rg]);

#pragma unroll
        for (int ks = 0; ks < 4; ks++) {
            bf16x8 ap = *(const bf16x8*)(Pst + (wave * 16 + r16) * 136 + ks * 32 + quad * 8);
#pragma unroll
            for (int nt = 0; nt < 4; nt++) {
                bf16x8 bv = *(const bf16x8*)(Vst + (nt * 16 + r16) * 138 + ks * 32 + quad * 8);
                accv[nt] = __builtin_amdgcn_mfma_f32_16x16x32_bf16(ap, bv, accv[nt], 0, 0, 0);
            }
        }
    }
#undef PRE

#pragma unroll
    for (int nt = 0; nt < 4; nt++)
#pragma unroll
        for (int rg = 0; rg < 4; rg++) {
            int rt = t0 + rowbase + rg;
            A2[((size_t)(b * TT + rt)) * EE + h * 64 + nt * 16 + r16] =
                f2b(accv[nt][rg] / l[rg]);
        }
}

extern "C" void kernel_launch(void* const* d_in, const int* in_sizes, int n_in,
                              void* d_out, int out_size, void* d_ws, size_t ws_size,
                              hipStream_t stream) {
    const float* hidden = (const float*)d_in[0];
    const float* pos    = (const float*)d_in[1];
    const float* chan   = (const float*)d_in[2];
    const float* Wq     = (const float*)d_in[3];
    const float* Wkv    = (const float*)d_in[4];
    const float* Wpos   = (const float*)d_in[5];
    const float* Wchan  = (const float*)d_in[6];
    const float* Wproj  = (const float*)d_in[7];
    const float* bias   = (const float*)d_in[8];

    // workspace carve: ~20.2 MB total
    u16* qb    = (u16*)d_ws;               // 2,097,152 u16 (4 MB)
    u16* kvb   = qb + 2097152;             // 1,048,576 u16 (2 MB)
    u16* A2    = kvb + 1048576;            // 2,097,152 u16 (4 MB)
    u16* vt    = A2 + 2097152;             //   524,288 u16 (1 MB)
    u16* hb    = vt + 524288;              // 2,097,152 u16 (4 MB) hidden bf16
    u16* btq   = hb + 2097152;             // 1,572,864 u16 (3 MB) [Wq;Wkv]^T bf16
    u16* btp   = btq + 1572864;            // 1,048,576 u16 (2 MB) Wproj^T bf16
    float* tkb = (float*)(btp + 1048576);  //    32,768 f32 (128 KB)
    float* ckb = tkb + 32768;              //     2,048 f32 (8 KB)

    dim3 blk(256);
    // one-time bf16 conversions + weight transposes + tkb/ckb zero
    k_prep<<<3584, blk, 0, stream>>>(hidden, Wq, Wkv, Wproj, hb, btq, btp, tkb);
    // tiny projections via split-K (pos + chan in one dispatch)
    sgemm_sk<<<dim3(12, 8), blk, 0, stream>>>(pos, Wpos, chan, Wchan, tkb, ckb);
    // fused q/kv projection via MFMA (V-half written transposed to vt)
    mgemm_qkv2<<<dim3(12, 16), blk, 0, stream>>>(hb, btq, qb, kvb, vt);
    // big-tile MFMA flash attention (time_att fused in-prologue) -> A2
    k_att4<<<dim3(16, 16, 2), blk, 0, stream>>>(qb, kvb, vt, tkb, ckb, bias, A2);
    // output projection via MFMA -> fp32 d_out
    mgemm_proj2<<<dim3(16, 16), blk, 0, stream>>>(A2, btp, (float*)d_out);
}